// Round 6
// baseline (190.320 us; speedup 1.0000x reference)
//
#include <hip/hip_runtime.h>
#include <hip/hip_cooperative_groups.h>
#include <stdint.h>

namespace cg = cooperative_groups;

#define EPS 1e-5f
#define T_DIM 16384
#define N_DIM 1024
#define K_DIM 1024

// ---------------- workspace layout (bytes) ----------------
// qx   int8  [16384][1024]  @ 0          (16 MiB)
// qw   int8  [1024][1024]   @ 16777216   (1 MiB)
// dq   f32   [16384]        @ 17825792   (64 KiB)   dq[t] = max(rowmax,EPS)/127
// part f64   [256]          @ 17891328   (2 KiB)

typedef int v4i __attribute__((ext_vector_type(4)));

#define BM 256
#define BN 256
#define BK 128

__device__ __forceinline__ void gld_lds16(const void* g, void* l) {
    __builtin_amdgcn_global_load_lds(
        (const __attribute__((address_space(1))) void*)g,
        (__attribute__((address_space(3))) void*)l, 16, 0, 0);
}

// Single cooperative kernel: phase1 (x-quant of own rows + |W| partials)
// -> grid.sync -> phase2 (mean + w-quant from registers) -> grid.sync ->
// phase3 (R0's proven 256^2 BK=128 GEMM, unchanged).
// 256 blocks x 512 thr, 128 KiB LDS -> 1 block/CU, all 256 co-resident.
__global__ __launch_bounds__(512, 2) void k_fused(
    const float* __restrict__ x, const float* __restrict__ w,
    const float* __restrict__ bias,
    char* __restrict__ qx, char* __restrict__ qw,
    float* __restrict__ dq, double* __restrict__ part,
    float* __restrict__ out) {
    __shared__ __attribute__((aligned(16))) char As[2][BM * BK];   // 2 x 32 KiB
    __shared__ __attribute__((aligned(16))) char Bs[2][BN * BK];   // 2 x 32 KiB

    const int tid  = threadIdx.x;
    const int lane = tid & 63;
    const int wid  = tid >> 6;

    // XCD-bijective work remap (same as R0): xcd = bid&7 owns 32 consecutive
    // works = 8 brows x 4 bcols -> 2 MiB qx slab + 1 MiB qw per XCD L2.
    const int bid  = blockIdx.x;
    const int work = (bid & 7) * 32 + (bid >> 3);
    const int brow = work >> 2;
    const int bcol = work & 3;
    const long arow0 = (long)brow * BM;
    const int  ncol0 = bcol * BN;

    // ---------------- phase 1a: x-quant of this block's 64 rows ----------
    // Block (brow,bcol) quantizes rows [arow0+bcol*64, +64): the 4 blocks
    // sharing brow (same XCD under the remap) cover the 256-row slab this
    // brow's GEMM reads -> qx write and read stay in the same XCD L2.
    // 2 rows in flight per wave (8 float4 outstanding) for HBM latency.
#define XQROW(vv, rowv)                                                       \
    {                                                                         \
        float m = 0.0f;                                                       \
        _Pragma("unroll")                                                     \
        for (int i = 0; i < 4; ++i)                                           \
            m = fmaxf(m, fmaxf(fmaxf(fabsf(vv[i].x), fabsf(vv[i].y)),         \
                               fmaxf(fabsf(vv[i].z), fabsf(vv[i].w))));       \
        _Pragma("unroll")                                                     \
        for (int s = 32; s > 0; s >>= 1) m = fmaxf(m, __shfl_xor(m, s));      \
        m = fmaxf(m, EPS);                                                    \
        if (lane == 0) dq[rowv] = m * (1.0f / 127.0f);                        \
        const float s = 127.0f / m;                                           \
        int* qrow = (int*)(qx + (long)(rowv) * K_DIM);                        \
        _Pragma("unroll")                                                     \
        for (int i = 0; i < 4; ++i) {                                         \
            float f0 = fminf(fmaxf(rintf(vv[i].x * s), -128.f), 127.f);       \
            float f1 = fminf(fmaxf(rintf(vv[i].y * s), -128.f), 127.f);       \
            float f2 = fminf(fmaxf(rintf(vv[i].z * s), -128.f), 127.f);       \
            float f3 = fminf(fmaxf(rintf(vv[i].w * s), -128.f), 127.f);       \
            int q0 = (int)f0, q1 = (int)f1, q2 = (int)f2, q3 = (int)f3;       \
            qrow[i * 64 + lane] = (q0 & 255) | ((q1 & 255) << 8) |            \
                                  ((q2 & 255) << 16) | ((q3 & 255) << 24);    \
        }                                                                     \
    }

    {
        const int rbase = (int)arow0 + bcol * 64;
#pragma unroll
        for (int it = 0; it < 4; ++it) {
            const int r0 = rbase + it * 16 + wid;     // waves 0..7
            const int r1 = r0 + 8;
            const float4* x0 = (const float4*)(x + (long)r0 * K_DIM);
            const float4* x1 = (const float4*)(x + (long)r1 * K_DIM);
            float4 v0[4], v1[4];
#pragma unroll
            for (int i = 0; i < 4; ++i) v0[i] = x0[i * 64 + lane];
#pragma unroll
            for (int i = 0; i < 4; ++i) v1[i] = x1[i * 64 + lane];
            XQROW(v0, r0);
            XQROW(v1, r1);
        }
    }

    // ---------------- phase 1b: |W| partial (f64, deterministic) ----------
    // Block's w slice (2 float4/thread) -- kept in registers for phase 2.
    const int wbase = bid * 1024 + tid * 2;           // float4 index
    const float4* w4 = (const float4*)w;
    const float4 va = w4[wbase];
    const float4 vb = w4[wbase + 1];
    {
        double s = (double)fabsf(va.x) + (double)fabsf(va.y) +
                   (double)fabsf(va.z) + (double)fabsf(va.w) +
                   (double)fabsf(vb.x) + (double)fabsf(vb.y) +
                   (double)fabsf(vb.z) + (double)fabsf(vb.w);
        double* redd = (double*)(&As[0][0]);          // LDS overlay (4 KiB)
        redd[tid] = s;
        __syncthreads();
#pragma unroll
        for (int st = 256; st > 0; st >>= 1) {
            if (tid < st) redd[tid] += redd[tid + st];
            __syncthreads();
        }
        if (tid == 0) part[bid] = redd[0];
    }

    __threadfence();
    cg::this_grid().sync();

    // ---------------- phase 2: mean (redundant, deterministic) + w-quant ----
    float wmean;
    {
        double* redd = (double*)(&As[0][0]);
        redd[tid] = (tid < 256) ? part[tid] : 0.0;
        __syncthreads();
#pragma unroll
        for (int st = 256; st > 0; st >>= 1) {
            if (tid < st) redd[tid] += redd[tid + st];
            __syncthreads();
        }
        const double mean = fmax(redd[0] / 1048576.0, (double)EPS);
        wmean = (float)mean;
        const double ws = 1.0 / mean;
        int q0 = max(-1, min(1, (int)rint((double)va.x * ws)));
        int q1 = max(-1, min(1, (int)rint((double)va.y * ws)));
        int q2 = max(-1, min(1, (int)rint((double)va.z * ws)));
        int q3 = max(-1, min(1, (int)rint((double)va.w * ws)));
        int p0 = (q0 & 255) | ((q1 & 255) << 8) | ((q2 & 255) << 16) | ((q3 & 255) << 24);
        q0 = max(-1, min(1, (int)rint((double)vb.x * ws)));
        q1 = max(-1, min(1, (int)rint((double)vb.y * ws)));
        q2 = max(-1, min(1, (int)rint((double)vb.z * ws)));
        q3 = max(-1, min(1, (int)rint((double)vb.w * ws)));
        int p1 = (q0 & 255) | ((q1 & 255) << 8) | ((q2 & 255) << 16) | ((q3 & 255) << 24);
        int2 pk; pk.x = p0; pk.y = p1;
        ((int2*)qw)[bid * 512 + tid] = pk;
    }

    __threadfence();
    cg::this_grid().sync();

    // ---------------- phase 3: R0's GEMM, unchanged ----------------------
    const int wr = wid >> 2;            // 2x4 wave grid; wave tile 128x64
    const int wc = wid & 3;

    // staging: off = tid*16 + p*8192; row = off/128, chunk = (off/16)&7.
    // Swizzle involution S(row,c) = c ^ (row&7) on global source AND on read
    // (rule #21): LDS[row][ch] holds G[row][ch ^ (row&7)].
    int s_row[4], s_src[4], s_off[4];
#pragma unroll
    for (int p = 0; p < 4; ++p) {
        int off = tid * 16 + p * 8192;
        int row = off >> 7;
        int ch  = (off >> 4) & 7;
        s_row[p] = row; s_src[p] = (ch ^ (row & 7)) * 16; s_off[p] = off;
    }

#define STAGE(k0_, buf_)                                                      \
    {                                                                         \
        _Pragma("unroll")                                                     \
        for (int p = 0; p < 4; ++p) {                                         \
            const char* gA = qx + ((arow0 + s_row[p]) << 10) + (k0_) + s_src[p]; \
            gld_lds16(gA, As[buf_] + s_off[p]);                               \
            const char* gB = qw + (((long)(ncol0 + s_row[p])) << 10) + (k0_) + s_src[p]; \
            gld_lds16(gB, Bs[buf_] + s_off[p]);                               \
        }                                                                     \
    }

    v4i acc[8][4] = {};

    const int r15 = lane & 15;
    const int cg_ = lane >> 4;          // k-chunk group 0..3
    const int sw  = lane & 7;           // read-side swizzle (row&7 == lane&7)

    STAGE(0, 0);
    __syncthreads();

#pragma unroll
    for (int k0 = 0; k0 < 8; ++k0) {             // K-steps of 128
        const int cur = k0 & 1;
        if (k0 < 7) STAGE((k0 + 1) * BK, cur ^ 1);    // prefetch next tile

#pragma unroll
        for (int ks = 0; ks < 2; ++ks) {         // two 64-wide k-slices
            const int c = ks * 4 + cg_;          // global 16B-chunk index 0..7
            const int rch = (c ^ sw) * 16;       // swizzled byte chunk in row
            v4i a[8], b[4];
#pragma unroll
            for (int m = 0; m < 8; ++m) {
                int row = wr * 128 + m * 16 + r15;
                a[m] = *(const v4i*)(As[cur] + row * BK + rch);
            }
#pragma unroll
            for (int n = 0; n < 4; ++n) {
                int row = wc * 64 + n * 16 + r15;
                b[n] = *(const v4i*)(Bs[cur] + row * BK + rch);
            }
#pragma unroll
            for (int m = 0; m < 8; ++m)
#pragma unroll
                for (int n = 0; n < 4; ++n)
                    acc[m][n] = __builtin_amdgcn_mfma_i32_16x16x64_i8(
                        a[m], b[n], acc[m][n], 0, 0, 0);
        }
        __syncthreads();   // one barrier per K-step (R0's proven schedule)
    }

    // epilogue: C/D layout col=lane&15, row=(lane>>4)*4+reg
    const int ocol = ncol0 + wc * 64 + r15;
    float bv[4];
#pragma unroll
    for (int n = 0; n < 4; ++n) bv[n] = bias[ocol + n * 16];
#pragma unroll
    for (int m = 0; m < 8; ++m) {
#pragma unroll
        for (int rr = 0; rr < 4; ++rr) {
            long orow = arow0 + wr * 128 + m * 16 + cg_ * 4 + rr;
            float d = dq[orow] * wmean;
#pragma unroll
            for (int n = 0; n < 4; ++n)
                out[orow * N_DIM + ocol + n * 16] = (float)acc[m][n][rr] * d + bv[n];
        }
    }
}

extern "C" void kernel_launch(void* const* d_in, const int* in_sizes, int n_in,
                              void* d_out, int out_size, void* d_ws, size_t ws_size,
                              hipStream_t stream) {
    (void)in_sizes; (void)n_in; (void)out_size; (void)ws_size;
    const float* x    = (const float*)d_in[0];
    const float* w    = (const float*)d_in[1];
    const float* bias = (const float*)d_in[2];
    float* out = (float*)d_out;

    char*   ws   = (char*)d_ws;
    char*   qx   = ws;
    char*   qw   = ws + 16777216;
    float*  dq   = (float*)(ws + 17825792);
    double* part = (double*)(ws + 17891328);

    void* args[] = {(void*)&x, (void*)&w, (void*)&bias, (void*)&qx,
                    (void*)&qw, (void*)&dq, (void*)&part, (void*)&out};
    hipLaunchCooperativeKernel((const void*)k_fused, dim3(256), dim3(512),
                               args, 0, stream);
}

// Round 7
// 49.254 us; speedup vs baseline: 3.8641x; 3.8641x over previous
//
#include <hip/hip_runtime.h>
#include <stdint.h>

#define EPS 1e-5f
#define T_DIM 16384
#define N_DIM 1024
#define K_DIM 1024

// ---------------- workspace layout (bytes) ----------------
// qx   int8  [16384][1024]  @ 0          (16 MiB)
// qw   int8  [1024][1024]   @ 16777216   (1 MiB)
// dq   f32   [16384]        @ 17825792   (64 KiB)   dq[t] = max(rowmax,EPS)/127
// part f64   [256]          @ 17891328   (2 KiB)
// meanf f32  [1]            @ 17893376

typedef int v4i __attribute__((ext_vector_type(4)));

// ---------- kernel 1: wave-per-row x-quant (blocks 0..4095) + |W| partial
// sums (blocks 4096..4351) ----------
// Row assignment XCD-aligned with k_gemm: xcd x writes qx rows
// [x*2048,(x+1)*2048) into its own L2 -- the slab k_gemm's xcd x reads.
__global__ __launch_bounds__(256) void k_xq_wabs(
    const float* __restrict__ x, const float* __restrict__ w,
    char* __restrict__ qx, float* __restrict__ dq, double* __restrict__ part) {
    const int bid = blockIdx.x;
    const int tid = threadIdx.x;

    if (bid < 4096) {
        // ---- per-row absmax + int8 quantize, one wave per row ----
        const int rb   = (bid & 7) * 512 + (bid >> 3);
        const int row  = rb * 4 + (tid >> 6);
        const int lane = tid & 63;
        const float4* xr = (const float4*)(x + (long)row * K_DIM);
        float4 v[4];
#pragma unroll
        for (int i = 0; i < 4; ++i) v[i] = xr[i * 64 + lane];
        float m = 0.0f;
#pragma unroll
        for (int i = 0; i < 4; ++i)
            m = fmaxf(m, fmaxf(fmaxf(fabsf(v[i].x), fabsf(v[i].y)),
                               fmaxf(fabsf(v[i].z), fabsf(v[i].w))));
#pragma unroll
        for (int s = 32; s > 0; s >>= 1) m = fmaxf(m, __shfl_xor(m, s));
        m = fmaxf(m, EPS);                        // jnp.clip(rowmax, EPS)
        if (lane == 0) dq[row] = m * (1.0f / 127.0f);
        const float s = 127.0f / m;               // act_scale
        int* qrow = (int*)(qx + (long)row * K_DIM);
#pragma unroll
        for (int i = 0; i < 4; ++i) {
            float f0 = fminf(fmaxf(rintf(v[i].x * s), -128.f), 127.f);
            float f1 = fminf(fmaxf(rintf(v[i].y * s), -128.f), 127.f);
            float f2 = fminf(fmaxf(rintf(v[i].z * s), -128.f), 127.f);
            float f3 = fminf(fmaxf(rintf(v[i].w * s), -128.f), 127.f);
            int q0 = (int)f0, q1 = (int)f1, q2 = (int)f2, q3 = (int)f3;
            qrow[i * 64 + lane] = (q0 & 255) | ((q1 & 255) << 8) |
                                  ((q2 & 255) << 16) | ((q3 & 255) << 24);
        }
    } else {
        // ---- partial |W| sums, f64, deterministic ----
        const int wb = bid - 4096;               // 0..255
        const int base = wb * 256 + tid;         // over 262144 float4
        const float4* w4 = (const float4*)w;
        double sum = 0.0;
#pragma unroll
        for (int i = 0; i < 4; ++i) {
            float4 v = w4[base + i * 65536];
            sum += (double)fabsf(v.x) + (double)fabsf(v.y) +
                   (double)fabsf(v.z) + (double)fabsf(v.w);
        }
        __shared__ double redd[256];
        redd[tid] = sum;
        __syncthreads();
#pragma unroll
        for (int st = 128; st > 0; st >>= 1) {
            if (tid < st) redd[tid] += redd[tid + st];
            __syncthreads();
        }
        if (tid == 0) part[wb] = redd[0];
    }
}

// ---------- kernel 2: finalize mean (redundant per block, deterministic)
//            + ternary-quantize W ----------
__global__ __launch_bounds__(256) void k_wquant(
    const float* __restrict__ w, char* __restrict__ qw,
    const double* __restrict__ part, float* __restrict__ meanf) {
    const int tid = threadIdx.x;
    __shared__ double red[256];
    red[tid] = part[tid];
    __syncthreads();
#pragma unroll
    for (int st = 128; st > 0; st >>= 1) {
        if (tid < st) red[tid] += red[tid + st];
        __syncthreads();
    }
    const double mean = fmax(red[0] / 1048576.0, (double)EPS);  // clip(mean,EPS)
    if (blockIdx.x == 0 && tid == 0) meanf[0] = (float)mean;
    const double ws = 1.0 / mean;                // w_scale
    const long i = (long)blockIdx.x * 256 + tid; // 262144 float4
    float4 v = ((const float4*)w)[i];
    int q0 = (int)rint((double)v.x * ws);
    int q1 = (int)rint((double)v.y * ws);
    int q2 = (int)rint((double)v.z * ws);
    int q3 = (int)rint((double)v.w * ws);
    q0 = max(-1, min(1, q0)); q1 = max(-1, min(1, q1));
    q2 = max(-1, min(1, q2)); q3 = max(-1, min(1, q3));
    int packed = (q0 & 255) | ((q1 & 255) << 8) | ((q2 & 255) << 16) | ((q3 & 255) << 24);
    ((int*)qw)[i] = packed;
}

// ---------- kernel 3: i8 GEMM, 256x128 tile, BK=128, 8 waves, dbuf LDS ----------
// The clean 2-round test: 512 independent blocks, LDS 96 KiB -> 1 block/CU,
// 2 dispatch rounds. Round-1 blocks retire per-CU and the scheduler backfills
// round-2 blocks whose K-loops overlap round-1's HBM store drain; only
// round-2's ~32 MB tail stays exposed. K-loop keeps R0's proven schedule:
// BK=128, 8 K-steps, one barrier/step, launch_bounds(512,2) (256 VGPR, no
// spill). Per K-step per SIMD: MFMA ~1305 cyc vs L2 staging ~857 -> covered.
#define BM 256
#define BN 128
#define BK 128

__device__ __forceinline__ void gld_lds16(const void* g, void* l) {
    __builtin_amdgcn_global_load_lds(
        (const __attribute__((address_space(1))) void*)g,
        (__attribute__((address_space(3))) void*)l, 16, 0, 0);
}

__global__ __launch_bounds__(512, 2) void k_gemm(
    const char* __restrict__ qx, const char* __restrict__ qw,
    const float* __restrict__ dq, const float* __restrict__ meanf_p,
    const float* __restrict__ bias, float* __restrict__ out) {
    __shared__ __attribute__((aligned(16))) char As[2][BM * BK];   // 2 x 32 KiB
    __shared__ __attribute__((aligned(16))) char Bs[2][BN * BK];   // 2 x 16 KiB

    const int tid  = threadIdx.x;
    const int lane = tid & 63;
    const int wid  = tid >> 6;
    const int wr   = wid >> 1;          // 4x2 wave grid; wave tile 64x64
    const int wc   = wid & 1;

    // 512 blocks = 64 brow x 8 bcol. XCD-bijective remap (512 % 8 == 0):
    // xcd = bid&7 owns works xcd*64..+63 = 8 consecutive brows x 8 bcols ->
    // 2 MiB qx slab (written by the same xcd in k1) + 1 MiB qw per XCD L2.
    const int bid  = blockIdx.x;
    const int work = (bid & 7) * 64 + (bid >> 3);
    const int brow = work >> 3;
    const int bcol = work & 7;
    const long arow0 = (long)brow * BM;
    const int  ncol0 = bcol * BN;

    // staging: off = tid*16 + p*8192; row = off/128, chunk = (off/16)&7.
    // A uses p=0..3 (32 KiB), B uses p=0..1 (16 KiB).
    // Swizzle involution S(row,c) = c ^ (row&7) on global source AND on read
    // (rule #21): LDS[row][ch] holds G[row][ch ^ (row&7)].
    int s_row[4], s_src[4], s_off[4];
#pragma unroll
    for (int p = 0; p < 4; ++p) {
        int off = tid * 16 + p * 8192;
        int row = off >> 7;
        int ch  = (off >> 4) & 7;
        s_row[p] = row; s_src[p] = (ch ^ (row & 7)) * 16; s_off[p] = off;
    }

#define STAGE(k0_, buf_)                                                      \
    {                                                                         \
        _Pragma("unroll")                                                     \
        for (int p = 0; p < 4; ++p) {                                         \
            const char* gA = qx + ((arow0 + s_row[p]) << 10) + (k0_) + s_src[p]; \
            gld_lds16(gA, As[buf_] + s_off[p]);                               \
        }                                                                     \
        _Pragma("unroll")                                                     \
        for (int p = 0; p < 2; ++p) {                                         \
            const char* gB = qw + (((long)(ncol0 + s_row[p])) << 10) + (k0_) + s_src[p]; \
            gld_lds16(gB, Bs[buf_] + s_off[p]);                               \
        }                                                                     \
    }

    v4i acc[4][4] = {};

    const int r15 = lane & 15;
    const int cg  = lane >> 4;          // k-chunk group 0..3
    const int sw  = lane & 7;           // read-side swizzle (row&7 == lane&7)

    STAGE(0, 0);
    __syncthreads();

#pragma unroll
    for (int k0 = 0; k0 < 8; ++k0) {             // K-steps of 128
        const int cur = k0 & 1;
        if (k0 < 7) STAGE((k0 + 1) * BK, cur ^ 1);    // prefetch next tile

#pragma unroll
        for (int ks = 0; ks < 2; ++ks) {         // two 64-wide k-slices
            const int c   = ks * 4 + cg;         // global 16B-chunk index 0..7
            const int rch = (c ^ sw) * 16;       // swizzled byte chunk in row
            v4i a[4], b[4];
#pragma unroll
            for (int m = 0; m < 4; ++m) {
                int row = wr * 64 + m * 16 + r15;
                a[m] = *(const v4i*)(As[cur] + row * BK + rch);
            }
#pragma unroll
            for (int n = 0; n < 4; ++n) {
                int row = wc * 64 + n * 16 + r15;
                b[n] = *(const v4i*)(Bs[cur] + row * BK + rch);
            }
#pragma unroll
            for (int m = 0; m < 4; ++m)
#pragma unroll
                for (int n = 0; n < 4; ++n)
                    acc[m][n] = __builtin_amdgcn_mfma_i32_16x16x64_i8(
                        a[m], b[n], acc[m][n], 0, 0, 0);
        }
        __syncthreads();   // one barrier per K-step (R0's proven schedule)
    }

    // epilogue: C/D layout col=lane&15, row=(lane>>4)*4+reg
    const float wmean = meanf_p[0];
    const int ocol = ncol0 + wc * 64 + r15;
    float bv[4];
#pragma unroll
    for (int n = 0; n < 4; ++n) bv[n] = bias[ocol + n * 16];
#pragma unroll
    for (int m = 0; m < 4; ++m) {
#pragma unroll
        for (int rr = 0; rr < 4; ++rr) {
            long orow = arow0 + wr * 64 + m * 16 + cg * 4 + rr;
            float d = dq[orow] * wmean;
#pragma unroll
            for (int n = 0; n < 4; ++n)
                out[orow * N_DIM + ocol + n * 16] = (float)acc[m][n][rr] * d + bv[n];
        }
    }
}

extern "C" void kernel_launch(void* const* d_in, const int* in_sizes, int n_in,
                              void* d_out, int out_size, void* d_ws, size_t ws_size,
                              hipStream_t stream) {
    (void)in_sizes; (void)n_in; (void)out_size; (void)ws_size;
    const float* x    = (const float*)d_in[0];
    const float* w    = (const float*)d_in[1];
    const float* bias = (const float*)d_in[2];
    float* out = (float*)d_out;

    char*   ws    = (char*)d_ws;
    char*   qx    = ws;
    char*   qw    = ws + 16777216;
    float*  dq    = (float*)(ws + 17825792);
    double* part  = (double*)(ws + 17891328);
    float*  meanf = (float*)(ws + 17893376);

    k_xq_wabs<<<dim3(4096 + 256), dim3(256), 0, stream>>>(x, w, qx, dq, part);
    k_wquant <<<dim3(1024),       dim3(256), 0, stream>>>(w, qw, part, meanf);
    k_gemm   <<<dim3(512),        dim3(512), 0, stream>>>(qx, qw, dq, meanf, bias, out);
}

// Round 8
// 45.364 us; speedup vs baseline: 4.1954x; 1.0858x over previous
//
#include <hip/hip_runtime.h>
#include <stdint.h>

#define EPS 1e-5f
#define T_DIM 16384
#define N_DIM 1024
#define K_DIM 1024

// ---------------- workspace layout (bytes) ----------------
// qx   int8  [16384][1024]  @ 0          (16 MiB)
// qw   int8  [1024][1024]   @ 16777216   (1 MiB)
// dq   f32   [16384]        @ 17825792   (64 KiB)   dq[t] = max(rowmax,EPS)/127
// part f64   [256]          @ 17891328   (2 KiB)
// meanf f32  [1]            @ 17893376

typedef int v4i __attribute__((ext_vector_type(4)));

// ---------- kernel 1: wave-per-row x-quant (blocks 0..4095) + |W| partial
// sums (blocks 4096..4351) ----------  [exact R0 version]
__global__ __launch_bounds__(256) void k_xq_wabs(
    const float* __restrict__ x, const float* __restrict__ w,
    char* __restrict__ qx, float* __restrict__ dq, double* __restrict__ part) {
    const int bid = blockIdx.x;
    const int tid = threadIdx.x;

    if (bid < 4096) {
        // ---- per-row absmax + int8 quantize, one wave per row ----
        const int row  = bid * 4 + (tid >> 6);
        const int lane = tid & 63;
        const float4* xr = (const float4*)(x + (long)row * K_DIM);
        float4 v[4];
#pragma unroll
        for (int i = 0; i < 4; ++i) v[i] = xr[i * 64 + lane];
        float m = 0.0f;
#pragma unroll
        for (int i = 0; i < 4; ++i)
            m = fmaxf(m, fmaxf(fmaxf(fabsf(v[i].x), fabsf(v[i].y)),
                               fmaxf(fabsf(v[i].z), fabsf(v[i].w))));
#pragma unroll
        for (int s = 32; s > 0; s >>= 1) m = fmaxf(m, __shfl_xor(m, s));
        m = fmaxf(m, EPS);                        // jnp.clip(rowmax, EPS)
        if (lane == 0) dq[row] = m * (1.0f / 127.0f);
        const float s = 127.0f / m;               // act_scale
        int* qrow = (int*)(qx + (long)row * K_DIM);
#pragma unroll
        for (int i = 0; i < 4; ++i) {
            float f0 = fminf(fmaxf(rintf(v[i].x * s), -128.f), 127.f);
            float f1 = fminf(fmaxf(rintf(v[i].y * s), -128.f), 127.f);
            float f2 = fminf(fmaxf(rintf(v[i].z * s), -128.f), 127.f);
            float f3 = fminf(fmaxf(rintf(v[i].w * s), -128.f), 127.f);
            int q0 = (int)f0, q1 = (int)f1, q2 = (int)f2, q3 = (int)f3;
            qrow[i * 64 + lane] = (q0 & 255) | ((q1 & 255) << 8) |
                                  ((q2 & 255) << 16) | ((q3 & 255) << 24);
        }
    } else {
        // ---- partial |W| sums, f64, deterministic ----
        const int wb = bid - 4096;               // 0..255
        const int base = wb * 256 + tid;         // over 262144 float4
        const float4* w4 = (const float4*)w;
        double sum = 0.0;
#pragma unroll
        for (int i = 0; i < 4; ++i) {
            float4 v = w4[base + i * 65536];
            sum += (double)fabsf(v.x) + (double)fabsf(v.y) +
                   (double)fabsf(v.z) + (double)fabsf(v.w);
        }
        __shared__ double redd[256];
        redd[tid] = sum;
        __syncthreads();
#pragma unroll
        for (int st = 128; st > 0; st >>= 1) {
            if (tid < st) redd[tid] += redd[tid + st];
            __syncthreads();
        }
        if (tid == 0) part[wb] = redd[0];
    }
}

// ---------- kernel 2: barrier-free mean + ternary-quantize W ----------
// 256 blocks x 1024 thr (1 dispatch round, was 4). Each WAVE redundantly
// reduces part[256] via 4 loads/lane (L2 broadcast) + 6-step shfl_xor
// butterfly -- no LDS, no __syncthreads, deterministic (same tree order in
// every wave). Replaces the 9-barrier LDS tree that dominated k2's time.
__global__ __launch_bounds__(1024) void k_wquant(
    const float* __restrict__ w, char* __restrict__ qw,
    const double* __restrict__ part, float* __restrict__ meanf) {
    const int tid  = threadIdx.x;
    const int lane = tid & 63;

    double s = part[lane] + part[lane + 64] + part[lane + 128] + part[lane + 192];
#pragma unroll
    for (int st = 32; st > 0; st >>= 1) s += __shfl_xor(s, st);

    const double mean = fmax(s / 1048576.0, (double)EPS);  // clip(mean,EPS)
    if (blockIdx.x == 0 && tid == 0) meanf[0] = (float)mean;
    const double ws = 1.0 / mean;                 // w_scale
    const long i = (long)blockIdx.x * 1024 + tid; // 262144 float4
    float4 v = ((const float4*)w)[i];
    int q0 = (int)rint((double)v.x * ws);
    int q1 = (int)rint((double)v.y * ws);
    int q2 = (int)rint((double)v.z * ws);
    int q3 = (int)rint((double)v.w * ws);
    q0 = max(-1, min(1, q0)); q1 = max(-1, min(1, q1));
    q2 = max(-1, min(1, q2)); q3 = max(-1, min(1, q3));
    int packed = (q0 & 255) | ((q1 & 255) << 8) | ((q2 & 255) << 16) | ((q3 & 255) << 24);
    ((int*)qw)[i] = packed;
}

// ---------- kernel 3: i8 GEMM, 256x256 tile, BK=128, 8 waves, dbuf LDS ----------
// [exact R0 version -- measured best across 8 structural variants]
#define BM 256
#define BN 256
#define BK 128

__device__ __forceinline__ void gld_lds16(const void* g, void* l) {
    __builtin_amdgcn_global_load_lds(
        (const __attribute__((address_space(1))) void*)g,
        (__attribute__((address_space(3))) void*)l, 16, 0, 0);
}

__global__ __launch_bounds__(512, 2) void k_gemm(
    const char* __restrict__ qx, const char* __restrict__ qw,
    const float* __restrict__ dq, const float* __restrict__ meanf_p,
    const float* __restrict__ bias, float* __restrict__ out) {
    __shared__ __attribute__((aligned(16))) char As[2][BM * BK];   // 2 x 32 KiB
    __shared__ __attribute__((aligned(16))) char Bs[2][BN * BK];   // 2 x 32 KiB

    const int tid  = threadIdx.x;
    const int lane = tid & 63;
    const int wid  = tid >> 6;
    const int wr   = wid >> 2;          // 2x4 wave grid; wave tile 128x64
    const int wc   = wid & 3;

    // 256 blocks = 64 brow x 4 bcol. XCD-bijective remap: xcd = bid&7 owns
    // works xcd*32..+31 = 8 consecutive brows x 4 bcols -> 2 MiB qx slab +
    // 1 MiB qw resident per XCD L2.
    const int bid  = blockIdx.x;
    const int work = (bid & 7) * 32 + (bid >> 3);
    const int brow = work >> 2;
    const int bcol = work & 3;
    const long arow0 = (long)brow * BM;
    const int  ncol0 = bcol * BN;

    // staging: thread covers LDS linear offsets tid*16 + p*8192, p=0..3
    // (32 KiB per matrix per buffer). row = off/128, chunk = (off/16)&7.
    // Swizzle involution S(row,c) = c ^ (row&7), applied on global source
    // AND on read (rule #21): LDS[row][ch] holds G[row][ch ^ (row&7)].
    int s_row[4], s_src[4], s_off[4];
#pragma unroll
    for (int p = 0; p < 4; ++p) {
        int off = tid * 16 + p * 8192;
        int row = off >> 7;
        int ch  = (off >> 4) & 7;
        int sch = ch ^ (row & 7);
        s_row[p] = row; s_src[p] = sch * 16; s_off[p] = off;
    }

#define STAGE(k0_, buf_)                                                      \
    {                                                                         \
        _Pragma("unroll")                                                     \
        for (int p = 0; p < 4; ++p) {                                         \
            const char* gA = qx + ((arow0 + s_row[p]) << 10) + (k0_) + s_src[p]; \
            gld_lds16(gA, As[buf_] + s_off[p]);                               \
            const char* gB = qw + (((long)(ncol0 + s_row[p])) << 10) + (k0_) + s_src[p]; \
            gld_lds16(gB, Bs[buf_] + s_off[p]);                               \
        }                                                                     \
    }

    v4i acc[8][4] = {};

    const int r15 = lane & 15;
    const int cg  = lane >> 4;          // k-chunk group 0..3
    const int sw  = lane & 7;           // read-side swizzle (row&7 == lane&7)

    STAGE(0, 0);
    __syncthreads();

#pragma unroll
    for (int k0 = 0; k0 < 8; ++k0) {             // K-steps of 128
        const int cur = k0 & 1;
        if (k0 < 7) STAGE((k0 + 1) * BK, cur ^ 1);    // prefetch next tile

#pragma unroll
        for (int ks = 0; ks < 2; ++ks) {         // two 64-wide k-slices
            const int c = ks * 4 + cg;           // global 16B-chunk index 0..7
            const int rch = (c ^ sw) * 16;       // swizzled byte chunk in row
            v4i a[8], b[4];
#pragma unroll
            for (int m = 0; m < 8; ++m) {
                int row = wr * 128 + m * 16 + r15;
                a[m] = *(const v4i*)(As[cur] + row * BK + rch);
            }
#pragma unroll
            for (int n = 0; n < 4; ++n) {
                int row = wc * 64 + n * 16 + r15;
                b[n] = *(const v4i*)(Bs[cur] + row * BK + rch);
            }
#pragma unroll
            for (int m = 0; m < 8; ++m)
#pragma unroll
                for (int n = 0; n < 4; ++n)
                    acc[m][n] = __builtin_amdgcn_mfma_i32_16x16x64_i8(
                        a[m], b[n], acc[m][n], 0, 0, 0);
        }
        __syncthreads();   // one barrier per K-step; 64 MFMA/wave cover the
                           // L2-resident staging latency before the drain
    }

    // epilogue: C/D layout col=lane&15, row=(lane>>4)*4+reg
    const float wmean = meanf_p[0];
    const int ocol = ncol0 + wc * 64 + r15;
    float bv[4];
#pragma unroll
    for (int n = 0; n < 4; ++n) bv[n] = bias[ocol + n * 16];
#pragma unroll
    for (int m = 0; m < 8; ++m) {
#pragma unroll
        for (int rr = 0; rr < 4; ++rr) {
            long orow = arow0 + wr * 128 + m * 16 + cg * 4 + rr;
            float d = dq[orow] * wmean;
#pragma unroll
            for (int n = 0; n < 4; ++n)
                out[orow * N_DIM + ocol + n * 16] = (float)acc[m][n][rr] * d + bv[n];
        }
    }
}

extern "C" void kernel_launch(void* const* d_in, const int* in_sizes, int n_in,
                              void* d_out, int out_size, void* d_ws, size_t ws_size,
                              hipStream_t stream) {
    (void)in_sizes; (void)n_in; (void)out_size; (void)ws_size;
    const float* x    = (const float*)d_in[0];
    const float* w    = (const float*)d_in[1];
    const float* bias = (const float*)d_in[2];
    float* out = (float*)d_out;

    char*   ws    = (char*)d_ws;
    char*   qx    = ws;
    char*   qw    = ws + 16777216;
    float*  dq    = (float*)(ws + 17825792);
    double* part  = (double*)(ws + 17891328);
    float*  meanf = (float*)(ws + 17893376);

    k_xq_wabs<<<dim3(4096 + 256), dim3(256),  0, stream>>>(x, w, qx, dq, part);
    k_wquant <<<dim3(256),        dim3(1024), 0, stream>>>(w, qw, part, meanf);
    k_gemm   <<<dim3(256),        dim3(512),  0, stream>>>(qx, qw, dq, meanf, bias, out);
}